// Round 4
// baseline (589.937 us; speedup 1.0000x reference)
//
#include <hip/hip_runtime.h>

#define E2 2048
#define DM 512

typedef __attribute__((ext_vector_type(8))) _Float16 half8;
typedef __attribute__((ext_vector_type(4))) _Float16 half4;
typedef __attribute__((ext_vector_type(8))) short short8;
typedef __attribute__((ext_vector_type(4))) short shortx4;
typedef __attribute__((ext_vector_type(4))) float floatx4;

// ---- async global->LDS stage of a 128x32 f16 tile (rows packed, 64B/row) ----
// LDS dest is LINEAR (global_load_lds requirement). Source chunk is permuted
// (chunk ^= row&3) and readers use slot (quad ^ (row&3)) -- kept from R3 for
// correctness-coupled symmetry (conflict count proved DMA-write-bound, not
// read-bound; this permutation is harmless).
// 512-thread variant: one 16B load per thread covers the whole 128x32 tile
__device__ __forceinline__ void stage_tile8(const _Float16* __restrict__ g, int stride,
                                            _Float16* lds, int tid) {
  const int r0 = tid >> 2;             // 0..127
  const int cs = ((tid & 3) ^ (r0 & 3)) * 8;  // swizzled source chunk (elems)
  const int wbase = (tid >> 6) * 512;  // wave-uniform LDS base (shorts); linear
  const _Float16* gp = g + (size_t)r0 * stride + cs;
  __builtin_amdgcn_global_load_lds(
      (const __attribute__((address_space(1))) unsigned int*)gp,
      (__attribute__((address_space(3))) unsigned int*)(lds + wbase), 16, 0, 0);
}

// ---- 8-wave (2x4) fragment kernels: per-wave 64x32 output, acc[4][2] ----
// single precision-component: 8 MFMAs / wave / K-step
__device__ __forceinline__ void mfma8(const _Float16* As, const _Float16* Bs,
                                      floatx4 acc[4][2], int wm, int wn, int lane) {
  const int m16 = lane & 15, quad = lane >> 4;
  const int sq = (quad ^ (m16 & 3)) * 8;
  half8 a[4];
#pragma unroll
  for (int i = 0; i < 4; ++i)
    a[i] = *(const half8*)(As + (wm * 64 + i * 16 + m16) * 32 + sq);
#pragma unroll
  for (int j = 0; j < 2; ++j) {
    const half8 b = *(const half8*)(Bs + (wn * 32 + j * 16 + m16) * 32 + sq);
#pragma unroll
    for (int i = 0; i < 4; ++i)
      acc[i][j] = __builtin_amdgcn_mfma_f32_16x16x32_f16(a[i], b, acc[i][j], 0, 0, 0);
  }
}

// split fp16x2: hh + lh + hl (24 MFMAs / wave / K-step)
__device__ __forceinline__ void mfma24(const _Float16* Ah, const _Float16* Al,
                                       const _Float16* Bh, const _Float16* Bl,
                                       floatx4 acc[4][2], int wm, int wn, int lane) {
  const int m16 = lane & 15, quad = lane >> 4;
  const int sq = (quad ^ (m16 & 3)) * 8;
  half8 ah[4], al[4];
#pragma unroll
  for (int i = 0; i < 4; ++i) {
    const int off = (wm * 64 + i * 16 + m16) * 32 + sq;
    ah[i] = *(const half8*)(Ah + off);
    al[i] = *(const half8*)(Al + off);
  }
#pragma unroll
  for (int j = 0; j < 2; ++j) {
    const int off = (wn * 32 + j * 16 + m16) * 32 + sq;
    const half8 bh = *(const half8*)(Bh + off);
    const half8 bl = *(const half8*)(Bl + off);
#pragma unroll
    for (int i = 0; i < 4; ++i) {
      acc[i][j] = __builtin_amdgcn_mfma_f32_16x16x32_f16(ah[i], bh, acc[i][j], 0, 0, 0);
      acc[i][j] = __builtin_amdgcn_mfma_f32_16x16x32_f16(al[i], bh, acc[i][j], 0, 0, 0);
      acc[i][j] = __builtin_amdgcn_mfma_f32_16x16x32_f16(ah[i], bl, acc[i][j], 0, 0, 0);
    }
  }
}

// ---- prep: split-convert fp32 -> fp16 hi/lo with scale ----
__global__ void split_conv_k(const float* __restrict__ src, _Float16* __restrict__ hi,
                             _Float16* __restrict__ lo, float scale, int n8) {
  int i = blockIdx.x * blockDim.x + threadIdx.x;
  const int stride = gridDim.x * blockDim.x;
  const float4* s4 = (const float4*)src;
  for (; i < n8; i += stride) {
    const float4 u = s4[2 * i], v = s4[2 * i + 1];
    const float g[8] = {u.x, u.y, u.z, u.w, v.x, v.y, v.z, v.w};
    half8 h, l;
#pragma unroll
    for (int t = 0; t < 8; ++t) {
      const float gv = g[t] * scale;
      const _Float16 hv = (_Float16)gv;
      h[t] = hv;
      l[t] = (_Float16)(gv - (float)hv);
    }
    ((half8*)hi)[i] = h;
    ((half8*)lo)[i] = l;
  }
}

__global__ void conv_k(const float* __restrict__ src, _Float16* __restrict__ dst, int n8) {
  int i = blockIdx.x * blockDim.x + threadIdx.x;
  const int stride = gridDim.x * blockDim.x;
  const float4* s4 = (const float4*)src;
  for (; i < n8; i += stride) {
    const float4 u = s4[2 * i], v = s4[2 * i + 1];
    const float g[8] = {u.x, u.y, u.z, u.w, v.x, v.y, v.z, v.w};
    half8 h;
#pragma unroll
    for (int t = 0; t < 8; ++t) h[t] = (_Float16)g[t];
    ((half8*)dst)[i] = h;
  }
}

// ---- prep: transpose W (k,n)->(n,k), scale x64, split fp16 hi/lo ----
__global__ void transw_k(const float* __restrict__ Wq, const float* __restrict__ Wk,
                         const float* __restrict__ Wv, _Float16* __restrict__ Wth,
                         _Float16* __restrict__ Wtl) {
  const int z = blockIdx.z;
  const float* W = (z == 0) ? Wq : (z == 1) ? Wk : Wv;
  __shared__ float t[32][33];
  const int n0 = blockIdx.x * 32, k0 = blockIdx.y * 32;
  const int tx = threadIdx.x, ty = threadIdx.y;
#pragma unroll
  for (int i = 0; i < 32; i += 8) t[ty + i][tx] = W[(size_t)(k0 + ty + i) * DM + n0 + tx];
  __syncthreads();
  const size_t zb = (size_t)z * DM * DM;
#pragma unroll
  for (int i = 0; i < 32; i += 8) {
    const float g = t[tx][ty + i] * 64.0f;
    const _Float16 h = (_Float16)g;
    const size_t o = zb + (size_t)(n0 + ty + i) * DM + (k0 + tx);
    Wth[o] = h;
    Wtl[o] = (_Float16)(g - (float)h);
  }
}

// ---- QKV projection: 512 threads, 8 waves (2x4) ----
__global__ __launch_bounds__(512, 4) void qkv_k(
    const _Float16* __restrict__ xh, const _Float16* __restrict__ xl,
    const _Float16* __restrict__ Wth, const _Float16* __restrict__ Wtl,
    const float* __restrict__ bqp, const float* __restrict__ bkp,
    const float* __restrict__ bvp,
    _Float16* __restrict__ qh, _Float16* __restrict__ ql,
    _Float16* __restrict__ kh, _Float16* __restrict__ kl,
    _Float16* __restrict__ vT) {
  __shared__ _Float16 Ah[2][4096], Al[2][4096], Bh[2][4096], Bl[2][4096];
  const int tid = threadIdx.x, lane = tid & 63, wv = tid >> 6;
  const int wm = wv >> 2, wn = wv & 3;
  // XCD-aware bijective remap (grid 128*4*3 = 1536, %8==0): co-locates blocks
  // sharing a W-tile (same bn,z) on one XCD's L2.
  const int flat = blockIdx.x + 128 * blockIdx.y + 512 * blockIdx.z;
  const int virt = (flat & 7) * 192 + (flat >> 3);
  const int bm = virt & 127, bn = (virt >> 7) & 3, z = virt >> 9;
  const bool split = (z < 2);
  const _Float16* Ash = xh + (size_t)bm * 128 * DM;
  const _Float16* Asl = xl + (size_t)bm * 128 * DM;
  const _Float16* Bsh = Wth + ((size_t)z * DM + bn * 128) * DM;
  const _Float16* Bsl = Wtl + ((size_t)z * DM + bn * 128) * DM;
  floatx4 acc[4][2];
  const floatx4 z4 = {0.f, 0.f, 0.f, 0.f};
#pragma unroll
  for (int i = 0; i < 4; ++i)
#pragma unroll
    for (int j = 0; j < 2; ++j) acc[i][j] = z4;

  stage_tile8(Ash, DM, Ah[0], tid);
  stage_tile8(Bsh, DM, Bh[0], tid);
  if (split) { stage_tile8(Asl, DM, Al[0], tid); stage_tile8(Bsl, DM, Bl[0], tid); }
  __syncthreads();
  for (int kt = 0; kt < 16; ++kt) {
    const int cur = kt & 1, nxt = cur ^ 1;
    if (kt < 15) {
      const int ko = (kt + 1) * 32;
      stage_tile8(Ash + ko, DM, Ah[nxt], tid);
      stage_tile8(Bsh + ko, DM, Bh[nxt], tid);
      if (split) { stage_tile8(Asl + ko, DM, Al[nxt], tid); stage_tile8(Bsl + ko, DM, Bl[nxt], tid); }
    }
    if (split) mfma24(Ah[cur], Al[cur], Bh[cur], Bl[cur], acc, wm, wn, lane);
    else       mfma8(Ah[cur], Bh[cur], acc, wm, wn, lane);
    __syncthreads();
  }
  const int m16 = lane & 15, quad = lane >> 4;
  const float* bias = (z == 0) ? bqp : (z == 1) ? bkp : bvp;
  if (split) {
    _Float16* oh = (z == 0) ? qh : kh;
    _Float16* ol = (z == 0) ? ql : kl;
#pragma unroll
    for (int j = 0; j < 2; ++j) {
      const int n = bn * 128 + wn * 32 + j * 16 + m16;
      const float bb = bias[n];
#pragma unroll
      for (int i = 0; i < 4; ++i) {
        const int m = bm * 128 + wm * 64 + i * 16 + quad * 4;
#pragma unroll
        for (int r = 0; r < 4; ++r) {
          const float val = acc[i][j][r] * (1.0f / 256.0f) + bb;  // undo x4 * x64
          const float v8 = val * 8.0f;                            // re-scale x8 for scores split
          const _Float16 h = (_Float16)v8;
          const _Float16 l = (_Float16)(v8 - (float)h);
          const size_t o = (size_t)(m + r) * DM + n;
          oh[o] = h; ol[o] = l;
        }
      }
    }
  } else {
#pragma unroll
    for (int j = 0; j < 2; ++j) {
      const int n = bn * 128 + wn * 32 + j * 16 + m16;  // d
      const float bb = bias[n];
#pragma unroll
      for (int i = 0; i < 4; ++i) {
        const int m = bm * 128 + wm * 64 + i * 16 + quad * 4;  // global token
        const int bidx = m >> 11, e0 = m & 2047;
        half4 pk;
#pragma unroll
        for (int r = 0; r < 4; ++r)
          pk[r] = (_Float16)(acc[i][j][r] * (1.0f / 256.0f) + bb);
        *(half4*)(vT + ((size_t)bidx * DM + n) * E2 + e0) = pk;  // v transposed [b][d][e]
      }
    }
  }
}

// ---- scores + blend -> f16 logits (unmasked; masking fused into smax_k) ----
__global__ __launch_bounds__(512, 4) void scores_k(
    const _Float16* __restrict__ qh, const _Float16* __restrict__ ql,
    const _Float16* __restrict__ kh, const _Float16* __restrict__ kl,
    const _Float16* __restrict__ qah, const _Float16* __restrict__ kah,
    const float* __restrict__ mc,
    const float* __restrict__ thrp, unsigned short* __restrict__ sc) {
  __shared__ _Float16 S[32768];  // 64 KiB, carved below
  _Float16* const AhB = S;           // 2 x 4096
  _Float16* const AlB = S + 8192;    // 2 x 4096
  _Float16* const BhB = S + 16384;   // 2 x 4096
  _Float16* const BlB = S + 24576;   // 2 x 4096
  const int tid = threadIdx.x, lane = tid & 63, wv = tid >> 6;
  const int wm = wv >> 2, wn = wv & 3;
  // XCD-aware bijective remap (grid 16*16*8 = 2048): one batch b per XCD ->
  // that batch's q/k hi/lo tiles become L2-resident.
  const int flat = blockIdx.x + 16 * blockIdx.y + 256 * blockIdx.z;
  const int virt = (flat & 7) * 256 + (flat >> 3);
  const int bf = virt & 15, be = (virt >> 4) & 15, b = virt >> 8;
  const _Float16* Ash = qh + ((size_t)b * E2 + be * 128) * DM;
  const _Float16* Asl = ql + ((size_t)b * E2 + be * 128) * DM;
  const _Float16* Bsh = kh + ((size_t)b * E2 + bf * 128) * DM;
  const _Float16* Bsl = kl + ((size_t)b * E2 + bf * 128) * DM;
  floatx4 accm[4][2];
  const floatx4 z4 = {0.f, 0.f, 0.f, 0.f};
#pragma unroll
  for (int i = 0; i < 4; ++i)
#pragma unroll
    for (int j = 0; j < 2; ++j) accm[i][j] = z4;

  stage_tile8(Ash, DM, AhB, tid);
  stage_tile8(Bsh, DM, BhB, tid);
  stage_tile8(Asl, DM, AlB, tid);
  stage_tile8(Bsl, DM, BlB, tid);
  __syncthreads();
  for (int kt = 0; kt < 16; ++kt) {
    const int cur = kt & 1, nxt = cur ^ 1;
    if (kt < 15) {
      const int ko = (kt + 1) * 32;
      stage_tile8(Ash + ko, DM, AhB + nxt * 4096, tid);
      stage_tile8(Bsh + ko, DM, BhB + nxt * 4096, tid);
      stage_tile8(Asl + ko, DM, AlB + nxt * 4096, tid);
      stage_tile8(Bsl + ko, DM, BlB + nxt * 4096, tid);
    }
    mfma24(AhB + cur * 4096, AlB + cur * 4096, BhB + cur * 4096, BlB + cur * 4096,
           accm, wm, wn, lane);
    __syncthreads();
  }
  // ---- aux (after main loop): sa = qa . ka / 8, K=64 ----
  floatx4 acca[4][2];
#pragma unroll
  for (int i = 0; i < 4; ++i)
#pragma unroll
    for (int j = 0; j < 2; ++j) acca[i][j] = z4;
  const _Float16* A2 = qah + ((size_t)b * E2 + be * 128) * 64;
  const _Float16* B2 = kah + ((size_t)b * E2 + bf * 128) * 64;
  stage_tile8(A2, 64, AhB, tid);
  stage_tile8(B2, 64, BhB, tid);
  stage_tile8(A2 + 32, 64, AhB + 4096, tid);
  stage_tile8(B2 + 32, 64, BhB + 4096, tid);
  __syncthreads();
  mfma8(AhB, BhB, acca, wm, wn, lane);
  mfma8(AhB + 4096, BhB + 4096, acca, wm, wn, lane);

  // ---- epilogue: LDS transpose (stride 132) + coalesced mc stream ----
  float* const sL = (float*)S;                 // 64 x 132 fp32
  _Float16* const saL = S + 16896;             // 64 x 132 f16
  const float thr = *thrp;
  const int m16 = lane & 15, quad = lane >> 4;
  const size_t rowbase0 = (size_t)b * E2 + be * 128;
#pragma unroll
  for (int h = 0; h < 2; ++h) {
    __syncthreads();  // previous LDS consumers (aux mfma / prior stream) done
    if (wm == h) {
#pragma unroll
      for (int j = 0; j < 2; ++j) {
        const int cl = wn * 32 + j * 16 + m16;
#pragma unroll
        for (int i = 0; i < 4; ++i) {
#pragma unroll
          for (int r = 0; r < 4; ++r) {
            const int rl = i * 16 + quad * 4 + r;
            sL[rl * 132 + cl] = accm[i][j][r] * (0.015625f * 0.044194173824159216f);
            saL[rl * 132 + cl] = (_Float16)(acca[i][j][r] * 0.125f);
          }
        }
      }
    }
    __syncthreads();
#pragma unroll
    for (int g = 0; g < 4; ++g) {
      const int tf = g * 2048 + tid * 4;
      const int rl = tf >> 7, cl = tf & 127;
      const size_t idx = (rowbase0 + h * 64 + rl) * E2 + bf * 128 + cl;
      const float4 c4 = *(const float4*)(mc + idx);
      const float4 s4v = *(const float4*)(sL + rl * 132 + cl);
      const half4 sa4 = *(const half4*)(saL + rl * 132 + cl);
      const float ss[4] = {s4v.x, s4v.y, s4v.z, s4v.w};
      const float cc[4] = {c4.x, c4.y, c4.z, c4.w};
      shortx4 o;
#pragma unroll
      for (int t = 0; t < 4; ++t) {
        float s = ss[t];
        const float sa = (float)sa4[t];
        if (sa != 0.0f && s > thr) s = (1.0f - cc[t]) * s + cc[t] * sa;
        union { _Float16 hh; unsigned short u; } u;
        u.hh = (_Float16)s;
        o[t] = (short)u.u;
      }
      *(shortx4*)(sc + idx) = o;
    }
  }
}

// ---- fused adjacency-mask + row softmax, in place on f16 scores ----
__global__ __launch_bounds__(256) void smax_k(unsigned short* __restrict__ sc,
                                              const int* __restrict__ adj) {
  const size_t row = blockIdx.x;
  unsigned short* p = sc + row * E2;
  const int* arow = adj + row * E2;
  const int tid = threadIdx.x, lane = tid & 63, wv = tid >> 6;
  const short8 raw = *(const short8*)(p + tid * 8);
  const int4 a0 = *(const int4*)(arow + tid * 8);
  const int4 a1 = *(const int4*)(arow + tid * 8 + 4);
  const int aa[8] = {a0.x, a0.y, a0.z, a0.w, a1.x, a1.y, a1.z, a1.w};
  float f[8];
#pragma unroll
  for (int t = 0; t < 8; ++t) {
    union { _Float16 h; short s; } u; u.s = raw[t];
    f[t] = aa[t] ? (float)u.h : -65504.0f;
  }
  float mx = f[0];
#pragma unroll
  for (int t = 1; t < 8; ++t) mx = fmaxf(mx, f[t]);
#pragma unroll
  for (int o = 32; o > 0; o >>= 1) mx = fmaxf(mx, __shfl_xor(mx, o, 64));
  __shared__ float red[8];
  if (lane == 0) red[wv] = mx;
  __syncthreads();
  mx = fmaxf(fmaxf(red[0], red[1]), fmaxf(red[2], red[3]));
  float ef[8], sum = 0.f;
#pragma unroll
  for (int t = 0; t < 8; ++t) { ef[t] = __expf(f[t] - mx); sum += ef[t]; }
#pragma unroll
  for (int o = 32; o > 0; o >>= 1) sum += __shfl_xor(sum, o, 64);
  if (lane == 0) red[4 + wv] = sum;
  __syncthreads();
  sum = (red[4] + red[5]) + (red[6] + red[7]);
  const float inv = 1.0f / sum;
  short8 ov;
#pragma unroll
  for (int t = 0; t < 8; ++t) {
    union { _Float16 h; short s; } u;
    u.h = (_Float16)(ef[t] * inv);
    ov[t] = u.s;
  }
  *(short8*)(p + tid * 8) = ov;
}

// ---- PV GEMM: attn (f16) @ v (f16, pre-transposed) -> fp32 out ----
// R4: 512 threads, 8 waves (2x4), acc[4][2], 32 KiB LDS -> 2-3 blocks/CU
// (16-24 waves/CU vs 8 before). Per-element K-chain identical to the old
// mfma16 form -> bit-identical output.
__global__ __launch_bounds__(512, 6) void pv_k(
    const _Float16* __restrict__ at, const _Float16* __restrict__ vT,
    float* __restrict__ out) {
  __shared__ _Float16 As[2][4096], Bs[2][4096];
  const int tid = threadIdx.x, lane = tid & 63, wv = tid >> 6;
  const int wm = wv >> 2, wn = wv & 3;
  // XCD-aware bijective remap (grid 4*16*8 = 512): one batch b per XCD ->
  // vT tile of that batch (2 MiB) becomes L2-resident.
  const int flat = blockIdx.x + 4 * blockIdx.y + 64 * blockIdx.z;
  const int virt = (flat & 7) * 64 + (flat >> 3);
  const int bd = virt & 3, be = (virt >> 2) & 15, b = virt >> 6;
  const _Float16* Asrc = at + ((size_t)b * E2 + be * 128) * E2;
  const _Float16* Bsrc = vT + ((size_t)b * DM + bd * 128) * E2;
  floatx4 acc[4][2];
  const floatx4 z4 = {0.f, 0.f, 0.f, 0.f};
#pragma unroll
  for (int i = 0; i < 4; ++i)
#pragma unroll
    for (int j = 0; j < 2; ++j) acc[i][j] = z4;
  stage_tile8(Asrc, E2, As[0], tid);
  stage_tile8(Bsrc, E2, Bs[0], tid);
  __syncthreads();
  for (int kt = 0; kt < 64; ++kt) {
    const int cur = kt & 1, nxt = cur ^ 1;
    if (kt < 63) {
      const int ko = (kt + 1) * 32;
      stage_tile8(Asrc + ko, E2, As[nxt], tid);
      stage_tile8(Bsrc + ko, E2, Bs[nxt], tid);
    }
    mfma8(As[cur], Bs[cur], acc, wm, wn, lane);
    __syncthreads();
  }
  const int m16 = lane & 15, quad = lane >> 4;
#pragma unroll
  for (int j = 0; j < 2; ++j) {
    const int d = bd * 128 + wn * 32 + j * 16 + m16;
#pragma unroll
    for (int i = 0; i < 4; ++i) {
      const int e0 = be * 128 + wm * 64 + i * 16 + quad * 4;
#pragma unroll
      for (int r = 0; r < 4; ++r)
        out[((size_t)b * E2 + e0 + r) * DM + d] = acc[i][j][r];
    }
  }
}

extern "C" void kernel_launch(void* const* d_in, const int* in_sizes, int n_in,
                              void* d_out, int out_size, void* d_ws, size_t ws_size,
                              hipStream_t stream) {
  const float* x   = (const float*)d_in[0];
  const float* qa  = (const float*)d_in[1];
  const float* ka  = (const float*)d_in[2];
  const int*   adj = (const int*)d_in[3];
  const float* mc  = (const float*)d_in[4];
  const float* Wq  = (const float*)d_in[5];
  const float* bq  = (const float*)d_in[6];
  const float* Wk  = (const float*)d_in[7];
  const float* bk  = (const float*)d_in[8];
  const float* Wv  = (const float*)d_in[9];
  const float* bv  = (const float*)d_in[10];
  const float* thr = (const float*)d_in[11];
  float* out = (float*)d_out;
  char* w = (char*)d_ws;
  const size_t MiB = 1ull << 20;
  _Float16* xh  = (_Float16*)(w + 0 * MiB);    // 16 MiB
  _Float16* xl  = (_Float16*)(w + 16 * MiB);   // 16 MiB
  _Float16* qhp = (_Float16*)(w + 32 * MiB);   // 16 MiB
  _Float16* qlp = (_Float16*)(w + 48 * MiB);   // 16 MiB
  _Float16* khp = (_Float16*)(w + 64 * MiB);   // 16 MiB
  _Float16* klp = (_Float16*)(w + 80 * MiB);   // 16 MiB
  _Float16* vT  = (_Float16*)(w + 96 * MiB);   // 16 MiB
  _Float16* Wth = (_Float16*)(w + 112 * MiB);  // 1.5 MiB
  _Float16* Wtl = (_Float16*)(w + 114 * MiB);  // 1.5 MiB
  _Float16* qah = (_Float16*)(w + 116 * MiB);  // 2 MiB
  _Float16* kah = (_Float16*)(w + 118 * MiB);  // 2 MiB
  unsigned short* sc = (unsigned short*)(w + 120 * MiB);  // 64 MiB

  split_conv_k<<<2048, 256, 0, stream>>>(x, xh, xl, 4.0f, (8 * E2 * DM) / 8);
  conv_k<<<256, 256, 0, stream>>>(qa, qah, (8 * E2 * 64) / 8);
  conv_k<<<256, 256, 0, stream>>>(ka, kah, (8 * E2 * 64) / 8);
  transw_k<<<dim3(16, 16, 3), dim3(32, 8), 0, stream>>>(Wq, Wk, Wv, Wth, Wtl);
  qkv_k<<<dim3(128, 4, 3), 512, 0, stream>>>(xh, xl, Wth, Wtl, bq, bk, bv,
                                             qhp, qlp, khp, klp, vT);
  scores_k<<<dim3(16, 16, 8), 512, 0, stream>>>(qhp, qlp, khp, klp, qah, kah,
                                                mc, thr, sc);
  smax_k<<<16384, 256, 0, stream>>>(sc, adj);
  pv_k<<<dim3(4, 16, 8), 512, 0, stream>>>((const _Float16*)sc, vT, out);
}

// Round 5
// 564.091 us; speedup vs baseline: 1.0458x; 1.0458x over previous
//
#include <hip/hip_runtime.h>

#define E2 2048
#define DM 512

typedef __attribute__((ext_vector_type(8))) _Float16 half8;
typedef __attribute__((ext_vector_type(4))) _Float16 half4;
typedef __attribute__((ext_vector_type(8))) short short8;
typedef __attribute__((ext_vector_type(4))) short shortx4;
typedef __attribute__((ext_vector_type(4))) float floatx4;

#define WAITV4 asm volatile("s_waitcnt vmcnt(4)" ::: "memory")
#define WAITV2 asm volatile("s_waitcnt vmcnt(2)" ::: "memory")
#define WAITV0 asm volatile("s_waitcnt vmcnt(0)" ::: "memory")
#define WAITL0 asm volatile("s_waitcnt lgkmcnt(0)" ::: "memory")
#define BARRIER __builtin_amdgcn_s_barrier()
#define SCHEDB __builtin_amdgcn_sched_barrier(0)

// ---- async global->LDS stage of a 128x32 f16 tile (rows packed, 64B/row) ----
// LDS dest LINEAR (global_load_lds requirement). Source chunk permuted
// (chunk ^= row&3); readers use slot (quad ^ (row&3)).
__device__ __forceinline__ void stage_tile8(const _Float16* __restrict__ g, int stride,
                                            _Float16* lds, int tid) {
  const int r0 = tid >> 2;             // 0..127
  const int cs = ((tid & 3) ^ (r0 & 3)) * 8;  // swizzled source chunk (elems)
  const int wbase = (tid >> 6) * 512;  // wave-uniform LDS base (shorts); linear
  const _Float16* gp = g + (size_t)r0 * stride + cs;
  __builtin_amdgcn_global_load_lds(
      (const __attribute__((address_space(1))) unsigned int*)gp,
      (__attribute__((address_space(3))) unsigned int*)(lds + wbase), 16, 0, 0);
}

// ---- 8-wave (2x4) fragment kernels: per-wave 64x32 output, acc[4][2] ----
__device__ __forceinline__ void mfma8(const _Float16* As, const _Float16* Bs,
                                      floatx4 acc[4][2], int wm, int wn, int lane) {
  const int m16 = lane & 15, quad = lane >> 4;
  const int sq = (quad ^ (m16 & 3)) * 8;
  half8 a[4];
#pragma unroll
  for (int i = 0; i < 4; ++i)
    a[i] = *(const half8*)(As + (wm * 64 + i * 16 + m16) * 32 + sq);
#pragma unroll
  for (int j = 0; j < 2; ++j) {
    const half8 b = *(const half8*)(Bs + (wn * 32 + j * 16 + m16) * 32 + sq);
#pragma unroll
    for (int i = 0; i < 4; ++i)
      acc[i][j] = __builtin_amdgcn_mfma_f32_16x16x32_f16(a[i], b, acc[i][j], 0, 0, 0);
  }
}

// split fp16x2: hh + lh + hl (24 MFMAs / wave / K-step)
__device__ __forceinline__ void mfma24(const _Float16* Ah, const _Float16* Al,
                                       const _Float16* Bh, const _Float16* Bl,
                                       floatx4 acc[4][2], int wm, int wn, int lane) {
  const int m16 = lane & 15, quad = lane >> 4;
  const int sq = (quad ^ (m16 & 3)) * 8;
  half8 ah[4], al[4];
#pragma unroll
  for (int i = 0; i < 4; ++i) {
    const int off = (wm * 64 + i * 16 + m16) * 32 + sq;
    ah[i] = *(const half8*)(Ah + off);
    al[i] = *(const half8*)(Al + off);
  }
#pragma unroll
  for (int j = 0; j < 2; ++j) {
    const int off = (wn * 32 + j * 16 + m16) * 32 + sq;
    const half8 bh = *(const half8*)(Bh + off);
    const half8 bl = *(const half8*)(Bl + off);
#pragma unroll
    for (int i = 0; i < 4; ++i) {
      acc[i][j] = __builtin_amdgcn_mfma_f32_16x16x32_f16(ah[i], bh, acc[i][j], 0, 0, 0);
      acc[i][j] = __builtin_amdgcn_mfma_f32_16x16x32_f16(al[i], bh, acc[i][j], 0, 0, 0);
      acc[i][j] = __builtin_amdgcn_mfma_f32_16x16x32_f16(ah[i], bl, acc[i][j], 0, 0, 0);
    }
  }
}

// ---- prep: split-convert fp32 -> fp16 hi/lo with scale ----
__global__ void split_conv_k(const float* __restrict__ src, _Float16* __restrict__ hi,
                             _Float16* __restrict__ lo, float scale, int n8) {
  int i = blockIdx.x * blockDim.x + threadIdx.x;
  const int stride = gridDim.x * blockDim.x;
  const float4* s4 = (const float4*)src;
  for (; i < n8; i += stride) {
    const float4 u = s4[2 * i], v = s4[2 * i + 1];
    const float g[8] = {u.x, u.y, u.z, u.w, v.x, v.y, v.z, v.w};
    half8 h, l;
#pragma unroll
    for (int t = 0; t < 8; ++t) {
      const float gv = g[t] * scale;
      const _Float16 hv = (_Float16)gv;
      h[t] = hv;
      l[t] = (_Float16)(gv - (float)hv);
    }
    ((half8*)hi)[i] = h;
    ((half8*)lo)[i] = l;
  }
}

__global__ void conv_k(const float* __restrict__ src, _Float16* __restrict__ dst, int n8) {
  int i = blockIdx.x * blockDim.x + threadIdx.x;
  const int stride = gridDim.x * blockDim.x;
  const float4* s4 = (const float4*)src;
  for (; i < n8; i += stride) {
    const float4 u = s4[2 * i], v = s4[2 * i + 1];
    const float g[8] = {u.x, u.y, u.z, u.w, v.x, v.y, v.z, v.w};
    half8 h;
#pragma unroll
    for (int t = 0; t < 8; ++t) h[t] = (_Float16)g[t];
    ((half8*)dst)[i] = h;
  }
}

// ---- prep: transpose W (k,n)->(n,k), scale x64, split fp16 hi/lo ----
__global__ void transw_k(const float* __restrict__ Wq, const float* __restrict__ Wk,
                         const float* __restrict__ Wv, _Float16* __restrict__ Wth,
                         _Float16* __restrict__ Wtl) {
  const int z = blockIdx.z;
  const float* W = (z == 0) ? Wq : (z == 1) ? Wk : Wv;
  __shared__ float t[32][33];
  const int n0 = blockIdx.x * 32, k0 = blockIdx.y * 32;
  const int tx = threadIdx.x, ty = threadIdx.y;
#pragma unroll
  for (int i = 0; i < 32; i += 8) t[ty + i][tx] = W[(size_t)(k0 + ty + i) * DM + n0 + tx];
  __syncthreads();
  const size_t zb = (size_t)z * DM * DM;
#pragma unroll
  for (int i = 0; i < 32; i += 8) {
    const float g = t[tx][ty + i] * 64.0f;
    const _Float16 h = (_Float16)g;
    const size_t o = zb + (size_t)(n0 + ty + i) * DM + (k0 + tx);
    Wth[o] = h;
    Wtl[o] = (_Float16)(g - (float)h);
  }
}

// ---- QKV projection: 512 threads, 8 waves (2x4), counted-vmcnt loop ----
__global__ __launch_bounds__(512, 4) void qkv_k(
    const _Float16* __restrict__ xh, const _Float16* __restrict__ xl,
    const _Float16* __restrict__ Wth, const _Float16* __restrict__ Wtl,
    const float* __restrict__ bqp, const float* __restrict__ bkp,
    const float* __restrict__ bvp,
    _Float16* __restrict__ qh, _Float16* __restrict__ ql,
    _Float16* __restrict__ kh, _Float16* __restrict__ kl,
    _Float16* __restrict__ vT) {
  __shared__ _Float16 Ah[2][4096], Al[2][4096], Bh[2][4096], Bl[2][4096];
  const int tid = threadIdx.x, lane = tid & 63, wv = tid >> 6;
  const int wm = wv >> 2, wn = wv & 3;
  // XCD mapping on the x-reuse axis: XCD s owns bm-slice [16s,16s+16) x all
  // (bn,z). Per-XCD x working set = 4 MiB (L2-resident), re-read 12x from L2.
  const int flat = blockIdx.x + 128 * (blockIdx.y + 4 * blockIdx.z);  // 0..1535
  const int s = flat & 7, k = flat >> 3;                              // k: 0..191
  const int bm = s * 16 + (k & 15);
  const int bnz = k >> 4;  // 0..11
  const int bn = bnz & 3, z = bnz >> 2;
  const bool split = (z < 2);
  const _Float16* Ash = xh + (size_t)bm * 128 * DM;
  const _Float16* Asl = xl + (size_t)bm * 128 * DM;
  const _Float16* Bsh = Wth + ((size_t)z * DM + bn * 128) * DM;
  const _Float16* Bsl = Wtl + ((size_t)z * DM + bn * 128) * DM;
  floatx4 acc[4][2];
  const floatx4 z4 = {0.f, 0.f, 0.f, 0.f};
#pragma unroll
  for (int i = 0; i < 4; ++i)
#pragma unroll
    for (int j = 0; j < 2; ++j) acc[i][j] = z4;

  stage_tile8(Ash, DM, Ah[0], tid);
  stage_tile8(Bsh, DM, Bh[0], tid);
  if (split) { stage_tile8(Asl, DM, Al[0], tid); stage_tile8(Bsl, DM, Bl[0], tid); }
  for (int kt = 0; kt < 16; ++kt) {
    const int cur = kt & 1, nxt = cur ^ 1;
    if (kt < 15) {
      const int ko = (kt + 1) * 32;
      stage_tile8(Ash + ko, DM, Ah[nxt], tid);
      stage_tile8(Bsh + ko, DM, Bh[nxt], tid);
      if (split) {
        stage_tile8(Asl + ko, DM, Al[nxt], tid);
        stage_tile8(Bsl + ko, DM, Bl[nxt], tid);
        WAITV4;  // cur's 4 loads (issued prev step) done; nxt's 4 stay in flight
      } else {
        WAITV2;  // cur's 2 done; nxt's 2 in flight
      }
    } else {
      WAITV0;
    }
    BARRIER;  // all waves' cur DMA landed
    SCHEDB;
    if (split) mfma24(Ah[cur], Al[cur], Bh[cur], Bl[cur], acc, wm, wn, lane);
    else       mfma8(Ah[cur], Bh[cur], acc, wm, wn, lane);
    WAITL0;   // own ds_reads of cur retired
    BARRIER;  // all reads of cur done -> next step may overwrite cur
    SCHEDB;
  }
  const int m16 = lane & 15, quad = lane >> 4;
  const float* bias = (z == 0) ? bqp : (z == 1) ? bkp : bvp;
  if (split) {
    _Float16* oh = (z == 0) ? qh : kh;
    _Float16* ol = (z == 0) ? ql : kl;
#pragma unroll
    for (int j = 0; j < 2; ++j) {
      const int n = bn * 128 + wn * 32 + j * 16 + m16;
      const float bb = bias[n];
#pragma unroll
      for (int i = 0; i < 4; ++i) {
        const int m = bm * 128 + wm * 64 + i * 16 + quad * 4;
#pragma unroll
        for (int r = 0; r < 4; ++r) {
          const float val = acc[i][j][r] * (1.0f / 256.0f) + bb;  // undo x4 * x64
          const float v8 = val * 8.0f;                            // re-scale x8 for scores split
          const _Float16 h = (_Float16)v8;
          const _Float16 l = (_Float16)(v8 - (float)h);
          const size_t o = (size_t)(m + r) * DM + n;
          oh[o] = h; ol[o] = l;
        }
      }
    }
  } else {
#pragma unroll
    for (int j = 0; j < 2; ++j) {
      const int n = bn * 128 + wn * 32 + j * 16 + m16;  // d
      const float bb = bias[n];
#pragma unroll
      for (int i = 0; i < 4; ++i) {
        const int m = bm * 128 + wm * 64 + i * 16 + quad * 4;  // global token
        const int bidx = m >> 11, e0 = m & 2047;
        half4 pk;
#pragma unroll
        for (int r = 0; r < 4; ++r)
          pk[r] = (_Float16)(acc[i][j][r] * (1.0f / 256.0f) + bb);
        *(half4*)(vT + ((size_t)bidx * DM + n) * E2 + e0) = pk;  // v transposed [b][d][e]
      }
    }
  }
}

// ---- scores + blend -> f16 logits (unmasked; masking fused into smax_k) ----
// R5: counted-vmcnt 2-barrier K-loop; XCD swizzle reverted (measured -6us).
__global__ __launch_bounds__(512, 4) void scores_k(
    const _Float16* __restrict__ qh, const _Float16* __restrict__ ql,
    const _Float16* __restrict__ kh, const _Float16* __restrict__ kl,
    const _Float16* __restrict__ qah, const _Float16* __restrict__ kah,
    const float* __restrict__ mc,
    const float* __restrict__ thrp, unsigned short* __restrict__ sc) {
  __shared__ _Float16 S[32768];  // 64 KiB, carved below
  _Float16* const AhB = S;           // 2 x 4096
  _Float16* const AlB = S + 8192;    // 2 x 4096
  _Float16* const BhB = S + 16384;   // 2 x 4096
  _Float16* const BlB = S + 24576;   // 2 x 4096
  const int tid = threadIdx.x, lane = tid & 63, wv = tid >> 6;
  const int wm = wv >> 2, wn = wv & 3;
  const int bf = blockIdx.x, be = blockIdx.y, b = blockIdx.z;
  const _Float16* Ash = qh + ((size_t)b * E2 + be * 128) * DM;
  const _Float16* Asl = ql + ((size_t)b * E2 + be * 128) * DM;
  const _Float16* Bsh = kh + ((size_t)b * E2 + bf * 128) * DM;
  const _Float16* Bsl = kl + ((size_t)b * E2 + bf * 128) * DM;
  floatx4 accm[4][2];
  const floatx4 z4 = {0.f, 0.f, 0.f, 0.f};
#pragma unroll
  for (int i = 0; i < 4; ++i)
#pragma unroll
    for (int j = 0; j < 2; ++j) accm[i][j] = z4;

  stage_tile8(Ash, DM, AhB, tid);
  stage_tile8(Bsh, DM, BhB, tid);
  stage_tile8(Asl, DM, AlB, tid);
  stage_tile8(Bsl, DM, BlB, tid);
  for (int kt = 0; kt < 16; ++kt) {
    const int cur = kt & 1, nxt = cur ^ 1;
    if (kt < 15) {
      const int ko = (kt + 1) * 32;
      stage_tile8(Ash + ko, DM, AhB + nxt * 4096, tid);
      stage_tile8(Bsh + ko, DM, BhB + nxt * 4096, tid);
      stage_tile8(Asl + ko, DM, AlB + nxt * 4096, tid);
      stage_tile8(Bsl + ko, DM, BlB + nxt * 4096, tid);
      WAITV4;  // cur's 4 loads done; nxt's 4 remain in flight across the barrier
    } else {
      WAITV0;
    }
    BARRIER;
    SCHEDB;
    mfma24(AhB + cur * 4096, AlB + cur * 4096, BhB + cur * 4096, BlB + cur * 4096,
           accm, wm, wn, lane);
    WAITL0;
    BARRIER;
    SCHEDB;
  }
  // ---- aux (after main loop): sa = qa . ka / 8, K=64 ----
  floatx4 acca[4][2];
#pragma unroll
  for (int i = 0; i < 4; ++i)
#pragma unroll
    for (int j = 0; j < 2; ++j) acca[i][j] = z4;
  const _Float16* A2 = qah + ((size_t)b * E2 + be * 128) * 64;
  const _Float16* B2 = kah + ((size_t)b * E2 + bf * 128) * 64;
  stage_tile8(A2, 64, AhB, tid);
  stage_tile8(B2, 64, BhB, tid);
  stage_tile8(A2 + 32, 64, AhB + 4096, tid);
  stage_tile8(B2 + 32, 64, BhB + 4096, tid);
  __syncthreads();
  mfma8(AhB, BhB, acca, wm, wn, lane);
  mfma8(AhB + 4096, BhB + 4096, acca, wm, wn, lane);

  // ---- epilogue: LDS transpose (stride 132) + coalesced mc stream ----
  float* const sL = (float*)S;                 // 64 x 132 fp32
  _Float16* const saL = S + 16896;             // 64 x 132 f16
  const float thr = *thrp;
  const int m16 = lane & 15, quad = lane >> 4;
  const size_t rowbase0 = (size_t)b * E2 + be * 128;
#pragma unroll
  for (int h = 0; h < 2; ++h) {
    __syncthreads();  // previous LDS consumers (aux mfma / prior stream) done
    if (wm == h) {
#pragma unroll
      for (int j = 0; j < 2; ++j) {
        const int cl = wn * 32 + j * 16 + m16;
#pragma unroll
        for (int i = 0; i < 4; ++i) {
#pragma unroll
          for (int r = 0; r < 4; ++r) {
            const int rl = i * 16 + quad * 4 + r;
            sL[rl * 132 + cl] = accm[i][j][r] * (0.015625f * 0.044194173824159216f);
            saL[rl * 132 + cl] = (_Float16)(acca[i][j][r] * 0.125f);
          }
        }
      }
    }
    __syncthreads();
#pragma unroll
    for (int g = 0; g < 4; ++g) {
      const int tf = g * 2048 + tid * 4;
      const int rl = tf >> 7, cl = tf & 127;
      const size_t idx = (rowbase0 + h * 64 + rl) * E2 + bf * 128 + cl;
      const float4 c4 = *(const float4*)(mc + idx);
      const float4 s4v = *(const float4*)(sL + rl * 132 + cl);
      const half4 sa4 = *(const half4*)(saL + rl * 132 + cl);
      const float ss[4] = {s4v.x, s4v.y, s4v.z, s4v.w};
      const float cc[4] = {c4.x, c4.y, c4.z, c4.w};
      shortx4 o;
#pragma unroll
      for (int t = 0; t < 4; ++t) {
        float s = ss[t];
        const float sa = (float)sa4[t];
        if (sa != 0.0f && s > thr) s = (1.0f - cc[t]) * s + cc[t] * sa;
        union { _Float16 hh; unsigned short u; } u;
        u.hh = (_Float16)s;
        o[t] = (short)u.u;
      }
      *(shortx4*)(sc + idx) = o;
    }
  }
}

// ---- fused adjacency-mask + row softmax, in place on f16 scores ----
__global__ __launch_bounds__(256) void smax_k(unsigned short* __restrict__ sc,
                                              const int* __restrict__ adj) {
  const size_t row = blockIdx.x;
  unsigned short* p = sc + row * E2;
  const int* arow = adj + row * E2;
  const int tid = threadIdx.x, lane = tid & 63, wv = tid >> 6;
  const short8 raw = *(const short8*)(p + tid * 8);
  const int4 a0 = *(const int4*)(arow + tid * 8);
  const int4 a1 = *(const int4*)(arow + tid * 8 + 4);
  const int aa[8] = {a0.x, a0.y, a0.z, a0.w, a1.x, a1.y, a1.z, a1.w};
  float f[8];
#pragma unroll
  for (int t = 0; t < 8; ++t) {
    union { _Float16 h; short s; } u; u.s = raw[t];
    f[t] = aa[t] ? (float)u.h : -65504.0f;
  }
  float mx = f[0];
#pragma unroll
  for (int t = 1; t < 8; ++t) mx = fmaxf(mx, f[t]);
#pragma unroll
  for (int o = 32; o > 0; o >>= 1) mx = fmaxf(mx, __shfl_xor(mx, o, 64));
  __shared__ float red[8];
  if (lane == 0) red[wv] = mx;
  __syncthreads();
  mx = fmaxf(fmaxf(red[0], red[1]), fmaxf(red[2], red[3]));
  float ef[8], sum = 0.f;
#pragma unroll
  for (int t = 0; t < 8; ++t) { ef[t] = __expf(f[t] - mx); sum += ef[t]; }
#pragma unroll
  for (int o = 32; o > 0; o >>= 1) sum += __shfl_xor(sum, o, 64);
  if (lane == 0) red[4 + wv] = sum;
  __syncthreads();
  sum = (red[4] + red[5]) + (red[6] + red[7]);
  const float inv = 1.0f / sum;
  short8 ov;
#pragma unroll
  for (int t = 0; t < 8; ++t) {
    union { _Float16 h; short s; } u;
    u.h = (_Float16)(ef[t] * inv);
    ov[t] = u.s;
  }
  *(short8*)(p + tid * 8) = ov;
}

// ---- PV GEMM: attn (f16) @ v (f16, pre-transposed) -> fp32 out ----
// R5: triple-buffered, ONE barrier per K-step, counted vmcnt(2). 48 KiB LDS,
// 3 blocks/CU. Per-element K-chain identical -> bit-identical output.
__global__ __launch_bounds__(512, 6) void pv_k(
    const _Float16* __restrict__ at, const _Float16* __restrict__ vT,
    float* __restrict__ out) {
  __shared__ _Float16 As[3][4096], Bs[3][4096];
  const int tid = threadIdx.x, lane = tid & 63, wv = tid >> 6;
  const int wm = wv >> 2, wn = wv & 3;
  // XCD remap: one batch b per XCD -> vT tile (2 MiB) L2-resident.
  const int flat = blockIdx.x + 4 * blockIdx.y + 64 * blockIdx.z;
  const int virt = (flat & 7) * 64 + (flat >> 3);
  const int bd = virt & 3, be = (virt >> 2) & 15, b = virt >> 6;
  const _Float16* Asrc = at + ((size_t)b * E2 + be * 128) * E2;
  const _Float16* Bsrc = vT + ((size_t)b * DM + bd * 128) * E2;
  floatx4 acc[4][2];
  const floatx4 z4 = {0.f, 0.f, 0.f, 0.f};
#pragma unroll
  for (int i = 0; i < 4; ++i)
#pragma unroll
    for (int j = 0; j < 2; ++j) acc[i][j] = z4;
  stage_tile8(Asrc, E2, As[0], tid);
  stage_tile8(Bsrc, E2, Bs[0], tid);
  int cur = 0;
  for (int kt = 0; kt < 64; ++kt) {
    const int nxt = (cur == 2) ? 0 : cur + 1;
    if (kt < 63) {
      const int ko = (kt + 1) * 32;
      stage_tile8(Asrc + ko, E2, As[nxt], tid);
      stage_tile8(Bsrc + ko, E2, Bs[nxt], tid);
      WAITV2;  // cur's 2 loads done; nxt's 2 in flight across the barrier
    } else {
      WAITV0;
    }
    BARRIER;  // all waves' cur DMA landed; (their prev-step lgkm drains make
    SCHEDB;   //  the 3-deep WAR rotation safe -- see loop tail)
    mfma8(As[cur], Bs[cur], acc, wm, wn, lane);
    WAITL0;   // own ds_reads retired before next barrier (WAR for buf reuse)
    cur = nxt;
  }
  const int m16 = lane & 15, quad = lane >> 4;
#pragma unroll
  for (int j = 0; j < 2; ++j) {
    const int d = bd * 128 + wn * 32 + j * 16 + m16;
#pragma unroll
    for (int i = 0; i < 4; ++i) {
      const int e0 = be * 128 + wm * 64 + i * 16 + quad * 4;
#pragma unroll
      for (int r = 0; r < 4; ++r)
        out[((size_t)b * E2 + e0 + r) * DM + d] = acc[i][j][r];
    }
  }
}

extern "C" void kernel_launch(void* const* d_in, const int* in_sizes, int n_in,
                              void* d_out, int out_size, void* d_ws, size_t ws_size,
                              hipStream_t stream) {
  const float* x   = (const float*)d_in[0];
  const float* qa  = (const float*)d_in[1];
  const float* ka  = (const float*)d_in[2];
  const int*   adj = (const int*)d_in[3];
  const float* mc  = (const float*)d_in[4];
  const float* Wq  = (const float*)d_in[5];
  const float* bq  = (const float*)d_in[6];
  const float* Wk  = (const float*)d_in[7];
  const float* bk  = (const float*)d_in[8];
  const float* Wv  = (const float*)d_in[9];
  const float* bv  = (const float*)d_in[10];
  const float* thr = (const float*)d_in[11];
  float* out = (float*)d_out;
  char* w = (char*)d_ws;
  const size_t MiB = 1ull << 20;
  _Float16* xh  = (_Float16*)(w + 0 * MiB);    // 16 MiB
  _Float16* xl  = (_Float16*)(w + 16 * MiB);   // 16 MiB
  _Float16* qhp = (_Float16*)(w + 32 * MiB);   // 16 MiB
  _Float16* qlp = (_Float16*)(w + 48 * MiB);   // 16 MiB
  _Float16* khp = (_Float16*)(w + 64 * MiB);   // 16 MiB
  _Float16* klp = (_Float16*)(w + 80 * MiB);   // 16 MiB
  _Float16* vT  = (_Float16*)(w + 96 * MiB);   // 16 MiB
  _Float16* Wth = (_Float16*)(w + 112 * MiB);  // 1.5 MiB
  _Float16* Wtl = (_Float16*)(w + 114 * MiB);  // 1.5 MiB
  _Float16* qah = (_Float16*)(w + 116 * MiB);  // 2 MiB
  _Float16* kah = (_Float16*)(w + 118 * MiB);  // 2 MiB
  unsigned short* sc = (unsigned short*)(w + 120 * MiB);  // 64 MiB

  split_conv_k<<<2048, 256, 0, stream>>>(x, xh, xl, 4.0f, (8 * E2 * DM) / 8);
  conv_k<<<256, 256, 0, stream>>>(qa, qah, (8 * E2 * 64) / 8);
  conv_k<<<256, 256, 0, stream>>>(ka, kah, (8 * E2 * 64) / 8);
  transw_k<<<dim3(16, 16, 3), dim3(32, 8), 0, stream>>>(Wq, Wk, Wv, Wth, Wtl);
  qkv_k<<<dim3(128, 4, 3), 512, 0, stream>>>(xh, xl, Wth, Wtl, bq, bk, bv,
                                             qhp, qlp, khp, klp, vT);
  scores_k<<<dim3(16, 16, 8), 512, 0, stream>>>(qhp, qlp, khp, klp, qah, kah,
                                                mc, thr, sc);
  smax_k<<<16384, 256, 0, stream>>>(sc, adj);
  pv_k<<<dim3(4, 16, 8), 512, 0, stream>>>((const _Float16*)sc, vT, out);
}

// Round 6
// 558.777 us; speedup vs baseline: 1.0558x; 1.0095x over previous
//
#include <hip/hip_runtime.h>

#define E2 2048
#define DM 512

typedef __attribute__((ext_vector_type(8))) _Float16 half8;
typedef __attribute__((ext_vector_type(4))) _Float16 half4;
typedef __attribute__((ext_vector_type(8))) short short8;
typedef __attribute__((ext_vector_type(4))) short shortx4;
typedef __attribute__((ext_vector_type(4))) float floatx4;

#define WAITV2 asm volatile("s_waitcnt vmcnt(2)" ::: "memory")
#define WAITV0 asm volatile("s_waitcnt vmcnt(0)" ::: "memory")
#define WAITL0 asm volatile("s_waitcnt lgkmcnt(0)" ::: "memory")
#define BARRIER __builtin_amdgcn_s_barrier()
#define SCHEDB __builtin_amdgcn_sched_barrier(0)

// ---- async global->LDS stage of a 128x32 f16 tile (rows packed, 64B/row) ----
// LDS dest LINEAR (global_load_lds requirement). Source chunk permuted
// (chunk ^= row&3); readers use slot (quad ^ (row&3)).
__device__ __forceinline__ void stage_tile8(const _Float16* __restrict__ g, int stride,
                                            _Float16* lds, int tid) {
  const int r0 = tid >> 2;             // 0..127
  const int cs = ((tid & 3) ^ (r0 & 3)) * 8;  // swizzled source chunk (elems)
  const int wbase = (tid >> 6) * 512;  // wave-uniform LDS base (shorts); linear
  const _Float16* gp = g + (size_t)r0 * stride + cs;
  __builtin_amdgcn_global_load_lds(
      (const __attribute__((address_space(1))) unsigned int*)gp,
      (__attribute__((address_space(3))) unsigned int*)(lds + wbase), 16, 0, 0);
}

// ---- 8-wave (2x4) fragment kernels: per-wave 64x32 output, acc[4][2] ----
__device__ __forceinline__ void mfma8(const _Float16* As, const _Float16* Bs,
                                      floatx4 acc[4][2], int wm, int wn, int lane) {
  const int m16 = lane & 15, quad = lane >> 4;
  const int sq = (quad ^ (m16 & 3)) * 8;
  half8 a[4];
#pragma unroll
  for (int i = 0; i < 4; ++i)
    a[i] = *(const half8*)(As + (wm * 64 + i * 16 + m16) * 32 + sq);
#pragma unroll
  for (int j = 0; j < 2; ++j) {
    const half8 b = *(const half8*)(Bs + (wn * 32 + j * 16 + m16) * 32 + sq);
#pragma unroll
    for (int i = 0; i < 4; ++i)
      acc[i][j] = __builtin_amdgcn_mfma_f32_16x16x32_f16(a[i], b, acc[i][j], 0, 0, 0);
  }
}

// split fp16x2: hh + lh + hl (24 MFMAs / wave / K-step)
__device__ __forceinline__ void mfma24(const _Float16* Ah, const _Float16* Al,
                                       const _Float16* Bh, const _Float16* Bl,
                                       floatx4 acc[4][2], int wm, int wn, int lane) {
  const int m16 = lane & 15, quad = lane >> 4;
  const int sq = (quad ^ (m16 & 3)) * 8;
  half8 ah[4], al[4];
#pragma unroll
  for (int i = 0; i < 4; ++i) {
    const int off = (wm * 64 + i * 16 + m16) * 32 + sq;
    ah[i] = *(const half8*)(Ah + off);
    al[i] = *(const half8*)(Al + off);
  }
#pragma unroll
  for (int j = 0; j < 2; ++j) {
    const int off = (wn * 32 + j * 16 + m16) * 32 + sq;
    const half8 bh = *(const half8*)(Bh + off);
    const half8 bl = *(const half8*)(Bl + off);
#pragma unroll
    for (int i = 0; i < 4; ++i) {
      acc[i][j] = __builtin_amdgcn_mfma_f32_16x16x32_f16(ah[i], bh, acc[i][j], 0, 0, 0);
      acc[i][j] = __builtin_amdgcn_mfma_f32_16x16x32_f16(al[i], bh, acc[i][j], 0, 0, 0);
      acc[i][j] = __builtin_amdgcn_mfma_f32_16x16x32_f16(ah[i], bl, acc[i][j], 0, 0, 0);
    }
  }
}

// ---- prep: split-convert fp32 -> fp16 hi/lo with scale ----
__global__ void split_conv_k(const float* __restrict__ src, _Float16* __restrict__ hi,
                             _Float16* __restrict__ lo, float scale, int n8) {
  int i = blockIdx.x * blockDim.x + threadIdx.x;
  const int stride = gridDim.x * blockDim.x;
  const float4* s4 = (const float4*)src;
  for (; i < n8; i += stride) {
    const float4 u = s4[2 * i], v = s4[2 * i + 1];
    const float g[8] = {u.x, u.y, u.z, u.w, v.x, v.y, v.z, v.w};
    half8 h, l;
#pragma unroll
    for (int t = 0; t < 8; ++t) {
      const float gv = g[t] * scale;
      const _Float16 hv = (_Float16)gv;
      h[t] = hv;
      l[t] = (_Float16)(gv - (float)hv);
    }
    ((half8*)hi)[i] = h;
    ((half8*)lo)[i] = l;
  }
}

// ---- fused prep: transw (blocks 0..767) + qa conv (768..1023) + ka conv ----
__global__ void prep_k(const float* __restrict__ Wq, const float* __restrict__ Wk,
                       const float* __restrict__ Wv, _Float16* __restrict__ Wth,
                       _Float16* __restrict__ Wtl,
                       const float* __restrict__ qa, _Float16* __restrict__ qah,
                       const float* __restrict__ ka, _Float16* __restrict__ kah) {
  const int bid = blockIdx.x, tid = threadIdx.x;
  if (bid < 768) {
    // transpose W (k,n)->(n,k), scale x64, split fp16 hi/lo
    const int z = bid >> 8;
    const float* W = (z == 0) ? Wq : (z == 1) ? Wk : Wv;
    __shared__ float t[32][33];
    const int n0 = (bid & 15) * 32, k0 = ((bid >> 4) & 15) * 32;
    const int tx = tid & 31, ty = tid >> 5;  // 32 x 8
#pragma unroll
    for (int i = 0; i < 32; i += 8) t[ty + i][tx] = W[(size_t)(k0 + ty + i) * DM + n0 + tx];
    __syncthreads();
    const size_t zb = (size_t)z * DM * DM;
#pragma unroll
    for (int i = 0; i < 32; i += 8) {
      const float g = t[tx][ty + i] * 64.0f;
      const _Float16 h = (_Float16)g;
      const size_t o = zb + (size_t)(n0 + ty + i) * DM + (k0 + tx);
      Wth[o] = h;
      Wtl[o] = (_Float16)(g - (float)h);
    }
  } else {
    // conv fp32 -> f16, 8 elems/thread, grid-stride over 256 blocks
    const bool isQ = bid < 1024;
    const float* src = isQ ? qa : ka;
    _Float16* dst = isQ ? qah : kah;
    const int n8 = (8 * E2 * 64) / 8;
    int i = (bid & 255) * 256 + tid;
    const float4* s4 = (const float4*)src;
    for (; i < n8; i += 256 * 256) {
      const float4 u = s4[2 * i], v = s4[2 * i + 1];
      const float g[8] = {u.x, u.y, u.z, u.w, v.x, v.y, v.z, v.w};
      half8 h;
#pragma unroll
      for (int t = 0; t < 8; ++t) h[t] = (_Float16)g[t];
      ((half8*)dst)[i] = h;
    }
  }
}

// ---- QKV projection: 512 threads, 8 waves (2x4), single-barrier loop ----
__global__ __launch_bounds__(512, 4) void qkv_k(
    const _Float16* __restrict__ xh, const _Float16* __restrict__ xl,
    const _Float16* __restrict__ Wth, const _Float16* __restrict__ Wtl,
    const float* __restrict__ bqp, const float* __restrict__ bkp,
    const float* __restrict__ bvp,
    _Float16* __restrict__ qh, _Float16* __restrict__ ql,
    _Float16* __restrict__ kh, _Float16* __restrict__ kl,
    _Float16* __restrict__ vT) {
  __shared__ _Float16 Ah[2][4096], Al[2][4096], Bh[2][4096], Bl[2][4096];
  const int tid = threadIdx.x, lane = tid & 63, wv = tid >> 6;
  const int wm = wv >> 2, wn = wv & 3;
  // XCD mapping on the x-reuse axis: XCD s owns bm-slice [16s,16s+16) x all
  // (bn,z). Per-XCD x working set = 4 MiB (L2-resident), re-read 12x from L2.
  const int flat = blockIdx.x + 128 * (blockIdx.y + 4 * blockIdx.z);  // 0..1535
  const int s = flat & 7, k = flat >> 3;                              // k: 0..191
  const int bm = s * 16 + (k & 15);
  const int bnz = k >> 4;  // 0..11
  const int bn = bnz & 3, z = bnz >> 2;
  const bool split = (z < 2);
  const _Float16* Ash = xh + (size_t)bm * 128 * DM;
  const _Float16* Asl = xl + (size_t)bm * 128 * DM;
  const _Float16* Bsh = Wth + ((size_t)z * DM + bn * 128) * DM;
  const _Float16* Bsl = Wtl + ((size_t)z * DM + bn * 128) * DM;
  floatx4 acc[4][2];
  const floatx4 z4 = {0.f, 0.f, 0.f, 0.f};
#pragma unroll
  for (int i = 0; i < 4; ++i)
#pragma unroll
    for (int j = 0; j < 2; ++j) acc[i][j] = z4;

  stage_tile8(Ash, DM, Ah[0], tid);
  stage_tile8(Bsh, DM, Bh[0], tid);
  if (split) { stage_tile8(Asl, DM, Al[0], tid); stage_tile8(Bsl, DM, Bl[0], tid); }
  __syncthreads();
  for (int kt = 0; kt < 16; ++kt) {
    const int cur = kt & 1, nxt = cur ^ 1;
    if (kt < 15) {
      const int ko = (kt + 1) * 32;
      stage_tile8(Ash + ko, DM, Ah[nxt], tid);
      stage_tile8(Bsh + ko, DM, Bh[nxt], tid);
      if (split) { stage_tile8(Asl + ko, DM, Al[nxt], tid); stage_tile8(Bsl + ko, DM, Bl[nxt], tid); }
    }
    if (split) mfma24(Ah[cur], Al[cur], Bh[cur], Bl[cur], acc, wm, wn, lane);
    else       mfma8(Ah[cur], Bh[cur], acc, wm, wn, lane);
    __syncthreads();
  }
  const int m16 = lane & 15, quad = lane >> 4;
  const float* bias = (z == 0) ? bqp : (z == 1) ? bkp : bvp;
  if (split) {
    _Float16* oh = (z == 0) ? qh : kh;
    _Float16* ol = (z == 0) ? ql : kl;
#pragma unroll
    for (int j = 0; j < 2; ++j) {
      const int n = bn * 128 + wn * 32 + j * 16 + m16;
      const float bb = bias[n];
#pragma unroll
      for (int i = 0; i < 4; ++i) {
        const int m = bm * 128 + wm * 64 + i * 16 + quad * 4;
#pragma unroll
        for (int r = 0; r < 4; ++r) {
          const float val = acc[i][j][r] * (1.0f / 256.0f) + bb;  // undo x4 * x64
          const float v8 = val * 8.0f;                            // re-scale x8 for scores split
          const _Float16 h = (_Float16)v8;
          const _Float16 l = (_Float16)(v8 - (float)h);
          const size_t o = (size_t)(m + r) * DM + n;
          oh[o] = h; ol[o] = l;
        }
      }
    }
  } else {
#pragma unroll
    for (int j = 0; j < 2; ++j) {
      const int n = bn * 128 + wn * 32 + j * 16 + m16;  // d
      const float bb = bias[n];
#pragma unroll
      for (int i = 0; i < 4; ++i) {
        const int m = bm * 128 + wm * 64 + i * 16 + quad * 4;  // global token
        const int bidx = m >> 11, e0 = m & 2047;
        half4 pk;
#pragma unroll
        for (int r = 0; r < 4; ++r)
          pk[r] = (_Float16)(acc[i][j][r] * (1.0f / 256.0f) + bb);
        *(half4*)(vT + ((size_t)bidx * DM + n) * E2 + e0) = pk;  // v transposed [b][d][e]
      }
    }
  }
}

// ---- scores + blend -> f16 logits (unmasked; masking fused into smax_k) ----
// R6: back to the measured-best R3 single-barrier double-buffered loop.
__global__ __launch_bounds__(512, 4) void scores_k(
    const _Float16* __restrict__ qh, const _Float16* __restrict__ ql,
    const _Float16* __restrict__ kh, const _Float16* __restrict__ kl,
    const _Float16* __restrict__ qah, const _Float16* __restrict__ kah,
    const float* __restrict__ mc,
    const float* __restrict__ thrp, unsigned short* __restrict__ sc) {
  __shared__ _Float16 S[32768];  // 64 KiB, carved below
  _Float16* const AhB = S;           // 2 x 4096
  _Float16* const AlB = S + 8192;    // 2 x 4096
  _Float16* const BhB = S + 16384;   // 2 x 4096
  _Float16* const BlB = S + 24576;   // 2 x 4096
  const int tid = threadIdx.x, lane = tid & 63, wv = tid >> 6;
  const int wm = wv >> 2, wn = wv & 3;
  const int bf = blockIdx.x, be = blockIdx.y, b = blockIdx.z;
  const _Float16* Ash = qh + ((size_t)b * E2 + be * 128) * DM;
  const _Float16* Asl = ql + ((size_t)b * E2 + be * 128) * DM;
  const _Float16* Bsh = kh + ((size_t)b * E2 + bf * 128) * DM;
  const _Float16* Bsl = kl + ((size_t)b * E2 + bf * 128) * DM;
  floatx4 accm[4][2];
  const floatx4 z4 = {0.f, 0.f, 0.f, 0.f};
#pragma unroll
  for (int i = 0; i < 4; ++i)
#pragma unroll
    for (int j = 0; j < 2; ++j) accm[i][j] = z4;

  stage_tile8(Ash, DM, AhB, tid);
  stage_tile8(Bsh, DM, BhB, tid);
  stage_tile8(Asl, DM, AlB, tid);
  stage_tile8(Bsl, DM, BlB, tid);
  __syncthreads();
  for (int kt = 0; kt < 16; ++kt) {
    const int cur = kt & 1, nxt = cur ^ 1;
    if (kt < 15) {
      const int ko = (kt + 1) * 32;
      stage_tile8(Ash + ko, DM, AhB + nxt * 4096, tid);
      stage_tile8(Bsh + ko, DM, BhB + nxt * 4096, tid);
      stage_tile8(Asl + ko, DM, AlB + nxt * 4096, tid);
      stage_tile8(Bsl + ko, DM, BlB + nxt * 4096, tid);
    }
    mfma24(AhB + cur * 4096, AlB + cur * 4096, BhB + cur * 4096, BlB + cur * 4096,
           accm, wm, wn, lane);
    __syncthreads();
  }
  // ---- aux (after main loop): sa = qa . ka / 8, K=64 ----
  floatx4 acca[4][2];
#pragma unroll
  for (int i = 0; i < 4; ++i)
#pragma unroll
    for (int j = 0; j < 2; ++j) acca[i][j] = z4;
  const _Float16* A2 = qah + ((size_t)b * E2 + be * 128) * 64;
  const _Float16* B2 = kah + ((size_t)b * E2 + bf * 128) * 64;
  stage_tile8(A2, 64, AhB, tid);
  stage_tile8(B2, 64, BhB, tid);
  stage_tile8(A2 + 32, 64, AhB + 4096, tid);
  stage_tile8(B2 + 32, 64, BhB + 4096, tid);
  __syncthreads();
  mfma8(AhB, BhB, acca, wm, wn, lane);
  mfma8(AhB + 4096, BhB + 4096, acca, wm, wn, lane);

  // ---- epilogue: LDS transpose (stride 132) + coalesced mc stream ----
  float* const sL = (float*)S;                 // 64 x 132 fp32
  _Float16* const saL = S + 16896;             // 64 x 132 f16
  const float thr = *thrp;
  const int m16 = lane & 15, quad = lane >> 4;
  const size_t rowbase0 = (size_t)b * E2 + be * 128;
#pragma unroll
  for (int h = 0; h < 2; ++h) {
    __syncthreads();  // previous LDS consumers (aux mfma / prior stream) done
    if (wm == h) {
#pragma unroll
      for (int j = 0; j < 2; ++j) {
        const int cl = wn * 32 + j * 16 + m16;
#pragma unroll
        for (int i = 0; i < 4; ++i) {
#pragma unroll
          for (int r = 0; r < 4; ++r) {
            const int rl = i * 16 + quad * 4 + r;
            sL[rl * 132 + cl] = accm[i][j][r] * (0.015625f * 0.044194173824159216f);
            saL[rl * 132 + cl] = (_Float16)(acca[i][j][r] * 0.125f);
          }
        }
      }
    }
    __syncthreads();
#pragma unroll
    for (int g = 0; g < 4; ++g) {
      const int tf = g * 2048 + tid * 4;
      const int rl = tf >> 7, cl = tf & 127;
      const size_t idx = (rowbase0 + h * 64 + rl) * E2 + bf * 128 + cl;
      const float4 c4 = *(const float4*)(mc + idx);
      const float4 s4v = *(const float4*)(sL + rl * 132 + cl);
      const half4 sa4 = *(const half4*)(saL + rl * 132 + cl);
      const float ss[4] = {s4v.x, s4v.y, s4v.z, s4v.w};
      const float cc[4] = {c4.x, c4.y, c4.z, c4.w};
      shortx4 o;
#pragma unroll
      for (int t = 0; t < 4; ++t) {
        float s = ss[t];
        const float sa = (float)sa4[t];
        if (sa != 0.0f && s > thr) s = (1.0f - cc[t]) * s + cc[t] * sa;
        union { _Float16 hh; unsigned short u; } u;
        u.hh = (_Float16)s;
        o[t] = (short)u.u;
      }
      *(shortx4*)(sc + idx) = o;
    }
  }
}

// ---- fused adjacency-mask + row softmax, 2 rows per 512-thread block ----
__global__ __launch_bounds__(512) void smax_k(unsigned short* __restrict__ sc,
                                              const int* __restrict__ adj) {
  const int tid = threadIdx.x, lane = tid & 63, wv = tid >> 6;  // 8 waves
  const int rh = tid >> 8;       // row half: 0..1 (waves 0-3 / 4-7)
  const int t = tid & 255;       // position within row
  const size_t row = (size_t)blockIdx.x * 2 + rh;
  unsigned short* p = sc + row * E2;
  const int* arow = adj + row * E2;
  const short8 raw = *(const short8*)(p + t * 8);
  const int4 a0 = *(const int4*)(arow + t * 8);
  const int4 a1 = *(const int4*)(arow + t * 8 + 4);
  const int aa[8] = {a0.x, a0.y, a0.z, a0.w, a1.x, a1.y, a1.z, a1.w};
  float f[8];
#pragma unroll
  for (int u = 0; u < 8; ++u) {
    union { _Float16 h; short s; } c; c.s = raw[u];
    f[u] = aa[u] ? (float)c.h : -65504.0f;
  }
  float mx = f[0];
#pragma unroll
  for (int u = 1; u < 8; ++u) mx = fmaxf(mx, f[u]);
#pragma unroll
  for (int o = 32; o > 0; o >>= 1) mx = fmaxf(mx, __shfl_xor(mx, o, 64));
  __shared__ float red[16];
  if (lane == 0) red[wv] = mx;
  __syncthreads();
  {
    const int base = rh * 4;
    mx = fmaxf(fmaxf(red[base + 0], red[base + 1]), fmaxf(red[base + 2], red[base + 3]));
  }
  float ef[8], sum = 0.f;
#pragma unroll
  for (int u = 0; u < 8; ++u) { ef[u] = __expf(f[u] - mx); sum += ef[u]; }
#pragma unroll
  for (int o = 32; o > 0; o >>= 1) sum += __shfl_xor(sum, o, 64);
  if (lane == 0) red[8 + wv] = sum;
  __syncthreads();
  {
    const int base = 8 + rh * 4;
    sum = (red[base + 0] + red[base + 1]) + (red[base + 2] + red[base + 3]);
  }
  const float inv = 1.0f / sum;
  short8 ov;
#pragma unroll
  for (int u = 0; u < 8; ++u) {
    union { _Float16 h; short s; } c;
    c.h = (_Float16)(ef[u] * inv);
    ov[u] = c.s;
  }
  *(short8*)(p + t * 8) = ov;
}

// ---- PV GEMM: attn (f16) @ v (f16, pre-transposed) -> fp32 out ----
// R5 form kept: triple-buffered, ONE barrier per K-step, counted vmcnt(2).
__global__ __launch_bounds__(512, 6) void pv_k(
    const _Float16* __restrict__ at, const _Float16* __restrict__ vT,
    float* __restrict__ out) {
  __shared__ _Float16 As[3][4096], Bs[3][4096];
  const int tid = threadIdx.x, lane = tid & 63, wv = tid >> 6;
  const int wm = wv >> 2, wn = wv & 3;
  // XCD remap: one batch b per XCD -> vT tile (2 MiB) L2-resident.
  const int flat = blockIdx.x + 4 * blockIdx.y + 64 * blockIdx.z;
  const int virt = (flat & 7) * 64 + (flat >> 3);
  const int bd = virt & 3, be = (virt >> 2) & 15, b = virt >> 6;
  const _Float16* Asrc = at + ((size_t)b * E2 + be * 128) * E2;
  const _Float16* Bsrc = vT + ((size_t)b * DM + bd * 128) * E2;
  floatx4 acc[4][2];
  const floatx4 z4 = {0.f, 0.f, 0.f, 0.f};
#pragma unroll
  for (int i = 0; i < 4; ++i)
#pragma unroll
    for (int j = 0; j < 2; ++j) acc[i][j] = z4;
  stage_tile8(Asrc, E2, As[0], tid);
  stage_tile8(Bsrc, E2, Bs[0], tid);
  int cur = 0;
  for (int kt = 0; kt < 64; ++kt) {
    const int nxt = (cur == 2) ? 0 : cur + 1;
    if (kt < 63) {
      const int ko = (kt + 1) * 32;
      stage_tile8(Asrc + ko, E2, As[nxt], tid);
      stage_tile8(Bsrc + ko, E2, Bs[nxt], tid);
      WAITV2;  // cur's 2 loads done; nxt's 2 in flight across the barrier
    } else {
      WAITV0;
    }
    BARRIER;
    SCHEDB;
    mfma8(As[cur], Bs[cur], acc, wm, wn, lane);
    WAITL0;   // own ds_reads retired before next barrier (WAR for buf reuse)
    cur = nxt;
  }
  const int m16 = lane & 15, quad = lane >> 4;
#pragma unroll
  for (int j = 0; j < 2; ++j) {
    const int d = bd * 128 + wn * 32 + j * 16 + m16;
#pragma unroll
    for (int i = 0; i < 4; ++i) {
      const int e0 = be * 128 + wm * 64 + i * 16 + quad * 4;
#pragma unroll
      for (int r = 0; r < 4; ++r)
        out[((size_t)b * E2 + e0 + r) * DM + d] = acc[i][j][r];
    }
  }
}

extern "C" void kernel_launch(void* const* d_in, const int* in_sizes, int n_in,
                              void* d_out, int out_size, void* d_ws, size_t ws_size,
                              hipStream_t stream) {
  const float* x   = (const float*)d_in[0];
  const float* qa  = (const float*)d_in[1];
  const float* ka  = (const float*)d_in[2];
  const int*   adj = (const int*)d_in[3];
  const float* mc  = (const float*)d_in[4];
  const float* Wq  = (const float*)d_in[5];
  const float* bq  = (const float*)d_in[6];
  const float* Wk  = (const float*)d_in[7];
  const float* bk  = (const float*)d_in[8];
  const float* Wv  = (const float*)d_in[9];
  const float* bv  = (const float*)d_in[10];
  const float* thr = (const float*)d_in[11];
  float* out = (float*)d_out;
  char* w = (char*)d_ws;
  const size_t MiB = 1ull << 20;
  _Float16* xh  = (_Float16*)(w + 0 * MiB);    // 16 MiB
  _Float16* xl  = (_Float16*)(w + 16 * MiB);   // 16 MiB
  _Float16* qhp = (_Float16*)(w + 32 * MiB);   // 16 MiB
  _Float16* qlp = (_Float16*)(w + 48 * MiB);   // 16 MiB
  _Float16* khp = (_Float16*)(w + 64 * MiB);   // 16 MiB
  _Float16* klp = (_Float16*)(w + 80 * MiB);   // 16 MiB
  _Float16* vT  = (_Float16*)(w + 96 * MiB);   // 16 MiB
  _Float16* Wth = (_Float16*)(w + 112 * MiB);  // 1.5 MiB
  _Float16* Wtl = (_Float16*)(w + 114 * MiB);  // 1.5 MiB
  _Float16* qah = (_Float16*)(w + 116 * MiB);  // 2 MiB
  _Float16* kah = (_Float16*)(w + 118 * MiB);  // 2 MiB
  unsigned short* sc = (unsigned short*)(w + 120 * MiB);  // 64 MiB

  split_conv_k<<<2048, 256, 0, stream>>>(x, xh, xl, 4.0f, (8 * E2 * DM) / 8);
  prep_k<<<1280, 256, 0, stream>>>(Wq, Wk, Wv, Wth, Wtl, qa, qah, ka, kah);
  qkv_k<<<dim3(128, 4, 3), 512, 0, stream>>>(xh, xl, Wth, Wtl, bq, bk, bv,
                                             qhp, qlp, khp, klp, vT);
  scores_k<<<dim3(16, 16, 8), 512, 0, stream>>>(qhp, qlp, khp, klp, qah, kah,
                                                mc, thr, sc);
  smax_k<<<8192, 512, 0, stream>>>(sc, adj);
  pv_k<<<dim3(4, 16, 8), 512, 0, stream>>>((const _Float16*)sc, vT, out);
}